// Round 4
// baseline (570.322 us; speedup 1.0000x reference)
//
#include <hip/hip_runtime.h>

#define NV 20000          // vertices
#define NE 4096           // hyperedges
#define FT 128            // features
#define NW_E 128          // u32 words per packed vertex row  (E/32)
#define NKC2 157          // 128-wide n-chunks (157*128 = 20096)
#define K_TOT 20096

typedef __attribute__((ext_vector_type(8))) short short8v;   // 8 bf16 — MFMA A/B frag
typedef __attribute__((ext_vector_type(4))) float float4v;   // 4 fp32 — MFMA C/D frag

__device__ __forceinline__ unsigned short f2bf(float f) {    // fp32 -> bf16 RNE
    unsigned u = __float_as_uint(f);
    u += 0x7FFFu + ((u >> 16) & 1u);
    return (unsigned short)(u >> 16);
}
// LDS tile: rows of 128 bf16 (256B), 16B chunks XOR-swizzled by row (c ^ r&15).
__device__ __forceinline__ int lds_off(int r, int c) {
    return r * 256 + ((c ^ (r & 15)) << 4);
}
// 16B LUT entry: byte -> 8 bf16 in {0.0, 1.0}
__device__ __forceinline__ uint4 lut_entry(int t) {
    uint4 e;
    e.x = ((t & 1) ? 0x3F80u : 0u) | ((t & 2) ? 0x3F800000u : 0u);
    e.y = ((t & 4) ? 0x3F80u : 0u) | ((t & 8) ? 0x3F800000u : 0u);
    e.z = ((t & 16) ? 0x3F80u : 0u) | ((t & 32) ? 0x3F800000u : 0u);
    e.w = ((t & 64) ? 0x3F80u : 0u) | ((t & 128) ? 0x3F800000u : 0u);
    return e;
}
// async 16B global->LDS. LDS dest = wave-uniform base + lane*16; producers
// pre-swizzle the GLOBAL layout so linear copy == swizzled LDS.
__device__ __forceinline__ void cp16(void* l, const void* g) {
    __builtin_amdgcn_global_load_lds((__attribute__((address_space(1))) void*)g,
                                     (__attribute__((address_space(3))) void*)l, 16, 0, 0);
}
// 32x32 bit transpose across each 32-lane half:
// input: lane i holds row i's 32 bits; output: lane j holds column j's 32 bits.
__device__ __forceinline__ unsigned bt32(unsigned x, int lane) {
    unsigned y;
    y = __shfl_xor(x, 16, 64);
    x = (lane & 16) ? ((x & 0xFFFF0000u) | ((y >> 16) & 0x0000FFFFu))
                    : ((x & 0x0000FFFFu) | ((y << 16) & 0xFFFF0000u));
    y = __shfl_xor(x, 8, 64);
    x = (lane & 8)  ? ((x & 0xFF00FF00u) | ((y >> 8) & 0x00FF00FFu))
                    : ((x & 0x00FF00FFu) | ((y << 8) & 0xFF00FF00u));
    y = __shfl_xor(x, 4, 64);
    x = (lane & 4)  ? ((x & 0xF0F0F0F0u) | ((y >> 4) & 0x0F0F0F0Fu))
                    : ((x & 0x0F0F0F0Fu) | ((y << 4) & 0xF0F0F0F0u));
    y = __shfl_xor(x, 2, 64);
    x = (lane & 2)  ? ((x & 0xCCCCCCCCu) | ((y >> 2) & 0x33333333u))
                    : ((x & 0x33333333u) | ((y << 2) & 0xCCCCCCCCu));
    y = __shfl_xor(x, 1, 64);
    x = (lane & 1)  ? ((x & 0xAAAAAAAAu) | ((y >> 1) & 0x55555555u))
                    : ((x & 0x55555555u) | ((y << 1) & 0xAAAAAAAAu));
    return x;
}

// ---------------- 1. pack H -> bits, COALESCED: wave = half row ----------------
// blocks 0..15 also zero de_cnt (accumulated by k_mm1 atomics, later dispatch).
__global__ __launch_bounds__(256) void k_pack(const int* __restrict__ H,
                                              unsigned* __restrict__ packed,
                                              float* __restrict__ dv,
                                              int* __restrict__ de_cnt) {
    __shared__ int cl[4];
    int t = threadIdx.x, wave = t >> 6, lane = t & 63;
    if (blockIdx.x < 16) de_cnt[blockIdx.x * 256 + t] = 0;
    int row = blockIdx.x * 2 + (wave >> 1);
    int half = wave & 1;
    const uint4* base = reinterpret_cast<const uint4*>(H) + (size_t)row * 1024 + half * 512 + lane * 8;
    unsigned m = 0;
#pragma unroll
    for (int i = 0; i < 8; ++i) {
        uint4 v = base[i];
        m |= (v.x ? 1u : 0u) << (i * 4 + 0);
        m |= (v.y ? 1u : 0u) << (i * 4 + 1);
        m |= (v.z ? 1u : 0u) << (i * 4 + 2);
        m |= (v.w ? 1u : 0u) << (i * 4 + 3);
    }
    packed[(size_t)row * NW_E + half * 64 + lane] = m;
    int c = __popc(m);
    for (int o = 32; o > 0; o >>= 1) c += __shfl_down(c, o, 64);
    if (lane == 0) cl[wave] = c;
    __syncthreads();
    if (t < 2) {
        int d = cl[t * 2] + cl[t * 2 + 1];
        dv[blockIdx.x * 2 + t] = d > 0 ? 1.0f / sqrtf((float)d) : 1.0f;
    }
}

// ---------------- 2. At[kc2][f][c-swz] = bf16(dv*X), PRE-SWIZZLED for cp16 ----------------
// n >= 20000 zero-filled: zero A-column guarantees pad-n contributions vanish in mm1.
__global__ __launch_bounds__(256) void k_mid(const float* __restrict__ X,
                                             const float* __restrict__ dv,
                                             unsigned short* __restrict__ At) {
    int t = threadIdx.x;
    int f = t & 127;
    int item = blockIdx.x * 2 + (t >> 7);     // 0..2511, 8 n each (2512*8 = 20096)
    int nbase = item * 8;
    unsigned short h[8];
#pragma unroll
    for (int i = 0; i < 8; ++i) {
        int n = nbase + i;
        float v = (n < NV) ? X[(size_t)n * FT + f] * dv[n] : 0.0f;
        h[i] = f2bf(v);
    }
    uint4 u;
    u.x = (unsigned)h[0] | ((unsigned)h[1] << 16);
    u.y = (unsigned)h[2] | ((unsigned)h[3] << 16);
    u.z = (unsigned)h[4] | ((unsigned)h[5] << 16);
    u.w = (unsigned)h[6] | ((unsigned)h[7] << 16);
    int kc2 = nbase >> 7;
    int c = (nbase >> 3) & 15;
    *reinterpret_cast<uint4*>(At + (size_t)kc2 * 16384 + f * 128 + ((c ^ (f & 15)) << 3)) = u;
}

// ---------------- 3. mm1: P[kp][e][f] = sum_n At[f][n] * H[n][e], split-K ----------------
// B bits come straight from `packed`, transposed IN-REGISTER via shfl_xor butterfly
// during staging. Edge degrees accumulate in registers, flush via 2 atomics/thread.
__global__ __launch_bounds__(256, 2) void k_mm1(const unsigned short* __restrict__ At,
                                                const unsigned* __restrict__ packed,
                                                float* __restrict__ P,
                                                int* __restrict__ de_cnt, int chunkK) {
    __shared__ __align__(16) unsigned char sA[32768];   // 128 f x 128 n bf16 (swz)
    __shared__ __align__(16) unsigned char sB[32768];   // 128 e x 128 n bf16 (swz)
    __shared__ __align__(16) uint4 slut[256];
    int t = threadIdx.x;
    slut[t] = lut_entry(t);

    int et = blockIdx.x & 31, kp = blockIdx.x >> 5;
    int e0 = et * 128;
    int kbeg = kp * chunkK;
    int kend = kbeg + chunkK; if (kend > K_TOT) kend = K_TOT;
    int iters = (kend - kbeg) >> 7; if (iters < 0) iters = 0;

    float4v acc[4][4];
#pragma unroll
    for (int i = 0; i < 4; ++i)
#pragma unroll
        for (int j = 0; j < 4; ++j)
#pragma unroll
            for (int r = 0; r < 4; ++r) acc[i][j][r] = 0.0f;

    int wave = t >> 6, lane = t & 63;
    int wm0 = (wave & 1) * 64, wc0 = (wave >> 1) * 64;
    int r0 = lane & 15, q = lane >> 4;

    // B-staging: 8 groups of 32 lanes. group g: n-subgroup ns=g&3 (32 n),
    // word pair wbase=(g>>2)*2 -> e-rows [wbase*32, wbase*32+64).
    int grp = t >> 5, l32 = t & 31;
    int ns = grp & 3;
    int wbase = (grp >> 2) * 2;
    int ecol = et * 4 + wbase;          // even -> uint2-aligned
    int de_c0 = 0, de_c1 = 0;

    auto ldB = [&](int it) {
        uint2 v; v.x = 0u; v.y = 0u;
        int n = kbeg + it * 128 + ns * 32 + l32;
        if (n < NV) v = *reinterpret_cast<const uint2*>(packed + (size_t)n * NW_E + ecol);
        return v;
    };
    uint2 bw; bw.x = 0u; bw.y = 0u;
    if (iters > 0) bw = ldB(0);
    __syncthreads();   // LUT ready

    const char* gA = reinterpret_cast<const char*>(At) + (size_t)(kbeg >> 7) * 32768 + wave * 8192 + lane * 16;
    char* lA = reinterpret_cast<char*>(sA) + wave * 8192;

    int rB0 = wbase * 32 + l32;         // e_local for word wbase
    int rB1 = rB0 + 32;                 // e_local for word wbase+1

    for (int it = 0; it < iters; ++it) {
        // A: 32KB async DMA (each wave 8x1KB, linear dest = pre-swizzled layout)
        const char* g = gA + (size_t)it * 32768;
#pragma unroll
        for (int j = 0; j < 8; ++j) cp16(lA + j * 1024, g + j * 1024);
        // B: prefetch next words, transpose current in-register, LUT-expand to sB
        uint2 nxt; nxt.x = 0u; nxt.y = 0u;
        if (it + 1 < iters) nxt = ldB(it + 1);
        {
            unsigned x0 = bt32(bw.x, lane);
            unsigned x1 = bt32(bw.y, lane);
            de_c0 += __popc(x0);
            de_c1 += __popc(x1);
#pragma unroll
            for (int c = 0; c < 4; ++c)
                *reinterpret_cast<uint4*>(sB + lds_off(rB0, ns * 4 + c)) = slut[(x0 >> (c * 8)) & 0xFF];
#pragma unroll
            for (int c = 0; c < 4; ++c)
                *reinterpret_cast<uint4*>(sB + lds_off(rB1, ns * 4 + c)) = slut[(x1 >> (c * 8)) & 0xFF];
            bw = nxt;
        }
        __syncthreads();
#pragma unroll
        for (int ks = 0; ks < 4; ++ks) {
            short8v a[4], bb[4];
#pragma unroll
            for (int mi = 0; mi < 4; ++mi)
                a[mi] = *reinterpret_cast<const short8v*>(sA + lds_off(wm0 + mi * 16 + r0, ks * 4 + q));
#pragma unroll
            for (int ci = 0; ci < 4; ++ci)
                bb[ci] = *reinterpret_cast<const short8v*>(sB + lds_off(wc0 + ci * 16 + r0, ks * 4 + q));
#pragma unroll
            for (int mi = 0; mi < 4; ++mi)
#pragma unroll
                for (int ci = 0; ci < 4; ++ci)
                    acc[mi][ci] = __builtin_amdgcn_mfma_f32_16x16x32_bf16(a[mi], bb[ci], acc[mi][ci], 0, 0, 0);
        }
        __syncthreads();
    }
    // flush per-lane edge-degree partials (each lane owns 2 fixed e-rows)
    atomicAdd(de_cnt + e0 + rB0, de_c0);
    atomicAdd(de_cnt + e0 + rB1, de_c1);
    // e-major epilogue: one float4 store per fragment (f = r contiguous)
    float* Pp = P + (size_t)kp * (4096 * 128);
#pragma unroll
    for (int mi = 0; mi < 4; ++mi)
#pragma unroll
        for (int ci = 0; ci < 4; ++ci) {
            int f = wm0 + mi * 16 + q * 4;
            int e = e0 + wc0 + ci * 16 + r0;
            *reinterpret_cast<float4v*>(Pp + (size_t)e * 128 + f) = acc[mi][ci];
        }
}

// ---------------- 4. fused reduce + (T^T W)^T * de -> Ut slabs; prefill out=bias ----------------
__global__ __launch_bounds__(256) void k_redut(const float* __restrict__ P,
                                               const float* __restrict__ W,
                                               const int* __restrict__ de_cnt,
                                               unsigned short* __restrict__ Ut,
                                               float* __restrict__ out,
                                               const float* __restrict__ bias, int S) {
    __shared__ float sT[8][132];    // +4 pad: W-phase reads conflict-free
    int t = threadIdx.x;
    // prefill out[n][g] = bias[g]  (mm2 atomically accumulates on top)
    {
        const float4* b4 = reinterpret_cast<const float4*>(bias);
        float4* o4 = reinterpret_cast<float4*>(out);
        for (int i = blockIdx.x * 256 + t; i < NV * 32; i += 512 * 256)
            o4[i] = b4[i & 31];
    }
    int e0 = blockIdx.x * 8;
    {
        int el = t >> 5, fq = (t & 31) * 4;
        const float* base = P + (size_t)(e0 + el) * 128 + fq;
        float4 s = {0.f, 0.f, 0.f, 0.f};
        for (int p = 0; p < S; ++p) {
            float4 v = *reinterpret_cast<const float4*>(base + (size_t)p * 524288);
            s.x += v.x; s.y += v.y; s.z += v.z; s.w += v.w;
        }
        *reinterpret_cast<float4*>(&sT[el][fq]) = s;
    }
    __syncthreads();
    int el = t & 7, gq = (t >> 3) * 4;
    int e = e0 + el;
    float a0 = 0, a1 = 0, a2 = 0, a3 = 0;
    for (int f = 0; f < 128; ++f) {
        float tv = sT[el][f];
        float4 wv = *reinterpret_cast<const float4*>(W + f * 128 + gq);
        a0 += tv * wv.x; a1 += tv * wv.y; a2 += tv * wv.z; a3 += tv * wv.w;
    }
    int cnt = de_cnt[e];
    float d = cnt > 0 ? 1.0f / (float)cnt : 1.0f;
    float av[4] = {a0, a1, a2, a3};
    int slabB = e >> 7, chi = (e >> 3) & 15, pos = e & 7;
#pragma unroll
    for (int k = 0; k < 4; ++k) {
        int g = gq + k, qg = g >> 5, gr = g & 31;
        Ut[(size_t)(qg * 32 + slabB) * 4096 + gr * 128 + ((chi ^ (gr & 15)) << 3) + pos] = f2bf(av[k] * d);
    }
}

// ---------------- 5. mm2 v2: block = 128n x 128g, e-split S2=4, atomic accumulate ----------------
// A bit-expansion done ONCE per (n-stripe, e-chunk) — no qg redundancy; per ks 8 frag
// reads feed 16 MFMA (2x better reuse). out pre-filled with bias by k_redut.
__global__ __launch_bounds__(256, 2) void k_mm2(const unsigned* __restrict__ packed,
                                                const unsigned short* __restrict__ Ut,
                                                const float* __restrict__ dv,
                                                float* __restrict__ out) {
    __shared__ __align__(16) unsigned char sA[32768];   // 128 n x 128 e bf16 (swz)
    __shared__ __align__(16) unsigned char sB[32768];   // 128 g x 128 e bf16 (swz)
    __shared__ __align__(16) uint4 slut[256];
    int t = threadIdx.x;
    slut[t] = lut_entry(t);

    int mt = blockIdx.x >> 2, es = blockIdx.x & 3;   // n-stripe, e-chunk (1024 e)
    int n0 = mt * 128;

    float4v acc[4][4];
#pragma unroll
    for (int i = 0; i < 4; ++i)
#pragma unroll
        for (int j = 0; j < 4; ++j)
#pragma unroll
            for (int r = 0; r < 4; ++r) acc[i][j][r] = 0.0f;

    int wave = t >> 6, lane = t & 63;
    int wm0 = (wave & 1) * 64, wg0 = (wave >> 1) * 64;
    int r0 = lane & 15, q = lane >> 4;

    int rA = t & 127, half = t >> 7, cb = half << 3;
    const uint4* arow4 = reinterpret_cast<const uint4*>(packed + (size_t)(n0 + rA) * NW_E) + es * 8;
    uint4 aw = arow4[0];   // rows >= NV read in-ws garbage; outputs guarded
    __syncthreads();       // LUT ready

    // B: wave w stages the 32-g slab qg=w of e-block (es*8+it): 8KB via 8 cp16/lane
    const char* gB = reinterpret_cast<const char*>(Ut) + ((size_t)wave * 32 + es * 8) * 8192 + lane * 16;
    char* lB = reinterpret_cast<char*>(sB) + wave * 8192;

    for (int it = 0; it < 8; ++it) {
        uint4 nxt = arow4[it + 1];      // 16B over-read at last iter stays in ws, never consumed
        {
            const char* g = gB + (size_t)it * 8192;
#pragma unroll
            for (int j = 0; j < 8; ++j) cp16(lB + j * 1024, g + j * 1024);
        }
        {
            unsigned wd0 = half ? aw.z : aw.x;
            unsigned wd1 = half ? aw.w : aw.y;
#pragma unroll
            for (int c = 0; c < 4; ++c)
                *reinterpret_cast<uint4*>(sA + lds_off(rA, cb + c)) = slut[(wd0 >> (c * 8)) & 0xFF];
#pragma unroll
            for (int c = 0; c < 4; ++c)
                *reinterpret_cast<uint4*>(sA + lds_off(rA, cb + 4 + c)) = slut[(wd1 >> (c * 8)) & 0xFF];
            aw = nxt;
        }
        __syncthreads();
#pragma unroll
        for (int ks = 0; ks < 4; ++ks) {
            short8v a[4], bb[4];
#pragma unroll
            for (int mi = 0; mi < 4; ++mi)
                a[mi] = *reinterpret_cast<const short8v*>(sA + lds_off(wm0 + mi * 16 + r0, ks * 4 + q));
#pragma unroll
            for (int ci = 0; ci < 4; ++ci)
                bb[ci] = *reinterpret_cast<const short8v*>(sB + lds_off(wg0 + ci * 16 + r0, ks * 4 + q));
#pragma unroll
            for (int mi = 0; mi < 4; ++mi)
#pragma unroll
                for (int ci = 0; ci < 4; ++ci)
                    acc[mi][ci] = __builtin_amdgcn_mfma_f32_16x16x32_bf16(a[mi], bb[ci], acc[mi][ci], 0, 0, 0);
        }
        __syncthreads();
    }
    // atomic accumulate: dv distributes over the e-chunk partial sums
#pragma unroll
    for (int mi = 0; mi < 4; ++mi)
#pragma unroll
        for (int ci = 0; ci < 4; ++ci) {
            int g = wg0 + ci * 16 + r0;
#pragma unroll
            for (int r = 0; r < 4; ++r) {
                int n = n0 + wm0 + mi * 16 + q * 4 + r;
                if (n < NV) atomicAdd(out + (size_t)n * 128 + g, dv[n] * acc[mi][ci][r]);
            }
        }
}

extern "C" void kernel_launch(void* const* d_in, const int* in_sizes, int n_in,
                              void* d_out, int out_size, void* d_ws, size_t ws_size,
                              hipStream_t stream) {
    const float* X    = (const float*)d_in[0];
    const int*   H    = (const int*)d_in[1];
    const float* W    = (const float*)d_in[2];
    const float* bias = (const float*)d_in[3];
    float* out = (float*)d_out;

    char* ws = (char*)d_ws;
    size_t off = 0;
    auto alloc = [&](size_t sz) { char* p = ws + off; off += (sz + 255) & ~(size_t)255; return p; };
    unsigned*       packed  = (unsigned*)alloc((size_t)NV * NW_E * 4);           // 10.24 MB
    unsigned short* At      = (unsigned short*)alloc((size_t)NKC2 * 16384 * 2);  //  5.14 MB
    unsigned short* Ut      = (unsigned short*)alloc((size_t)FT * NE * 2);       //  1.05 MB
    float*          dv      = (float*)alloc((size_t)NV * 4);
    int*            de_cnt  = (int*)alloc((size_t)NE * 4);
    size_t fixed = off;

    long long avail = (long long)ws_size - (long long)fixed;
    int S = (int)(avail / (128LL * 4096 * 4));
    if (S > 16) S = 16;
    if (S < 1) S = 1;
    float* P1 = (float*)(ws + fixed);
    int chunkK = ((NKC2 + S - 1) / S) * 128;

    k_pack  <<<NV / 2, 256, 0, stream>>>(H, packed, dv, de_cnt);
    k_mid   <<<1256, 256, 0, stream>>>(X, dv, At);
    k_mm1   <<<32 * S, 256, 0, stream>>>(At, packed, P1, de_cnt, chunkK);
    k_redut <<<512, 256, 0, stream>>>(P1, W, de_cnt, Ut, out, bias, S);
    k_mm2   <<<628, 256, 0, stream>>>(packed, Ut, dv, out);
}

// Round 5
// 559.331 us; speedup vs baseline: 1.0196x; 1.0196x over previous
//
#include <hip/hip_runtime.h>

#define NV 20000          // vertices
#define NE 4096           // hyperedges
#define FT 128            // features
#define NW_E 128          // u32 words per packed vertex row  (E/32)
#define NKC2 157          // 128-wide n-chunks (157*128 = 20096)
#define K_TOT 20096

typedef __attribute__((ext_vector_type(8))) short short8v;   // 8 bf16 — MFMA A/B frag
typedef __attribute__((ext_vector_type(4))) float float4v;   // 4 fp32 — MFMA C/D frag

__device__ __forceinline__ unsigned short f2bf(float f) {    // fp32 -> bf16 RNE
    unsigned u = __float_as_uint(f);
    u += 0x7FFFu + ((u >> 16) & 1u);
    return (unsigned short)(u >> 16);
}
// LDS tile: rows of 128 bf16 (256B), 16B chunks XOR-swizzled by row (c ^ r&15).
__device__ __forceinline__ int lds_off(int r, int c) {
    return r * 256 + ((c ^ (r & 15)) << 4);
}
// VALU bit->bf16 expansion: 8 bits -> 8 bf16 in {0.0, 1.0} (16B). Replaces the
// LDS byte-LUT, whose random per-lane b128 gathers were ~8-way bank-conflicted.
__device__ __forceinline__ uint4 expand8v(unsigned b) {
    uint4 e;
    e.x = ((b & 1u)   ? 0x3F80u : 0u) | ((b & 2u)   ? 0x3F800000u : 0u);
    e.y = ((b & 4u)   ? 0x3F80u : 0u) | ((b & 8u)   ? 0x3F800000u : 0u);
    e.z = ((b & 16u)  ? 0x3F80u : 0u) | ((b & 32u)  ? 0x3F800000u : 0u);
    e.w = ((b & 64u)  ? 0x3F80u : 0u) | ((b & 128u) ? 0x3F800000u : 0u);
    return e;
}
// async 16B global->LDS. LDS dest = wave-uniform base + lane*16; producers
// pre-swizzle the GLOBAL layout so linear copy == swizzled LDS.
__device__ __forceinline__ void cp16(void* l, const void* g) {
    __builtin_amdgcn_global_load_lds((__attribute__((address_space(1))) void*)g,
                                     (__attribute__((address_space(3))) void*)l, 16, 0, 0);
}
// 32x32 bit transpose across each 32-lane half:
// input: lane i holds row i's 32 bits; output: lane j holds column j's 32 bits.
__device__ __forceinline__ unsigned bt32(unsigned x, int lane) {
    unsigned y;
    y = __shfl_xor(x, 16, 64);
    x = (lane & 16) ? ((x & 0xFFFF0000u) | ((y >> 16) & 0x0000FFFFu))
                    : ((x & 0x0000FFFFu) | ((y << 16) & 0xFFFF0000u));
    y = __shfl_xor(x, 8, 64);
    x = (lane & 8)  ? ((x & 0xFF00FF00u) | ((y >> 8) & 0x00FF00FFu))
                    : ((x & 0x00FF00FFu) | ((y << 8) & 0xFF00FF00u));
    y = __shfl_xor(x, 4, 64);
    x = (lane & 4)  ? ((x & 0xF0F0F0F0u) | ((y >> 4) & 0x0F0F0F0Fu))
                    : ((x & 0x0F0F0F0Fu) | ((y << 4) & 0xF0F0F0F0u));
    y = __shfl_xor(x, 2, 64);
    x = (lane & 2)  ? ((x & 0xCCCCCCCCu) | ((y >> 2) & 0x33333333u))
                    : ((x & 0x33333333u) | ((y << 2) & 0xCCCCCCCCu));
    y = __shfl_xor(x, 1, 64);
    x = (lane & 1)  ? ((x & 0xAAAAAAAAu) | ((y >> 1) & 0x55555555u))
                    : ((x & 0x55555555u) | ((y << 1) & 0xAAAAAAAAu));
    return x;
}

// ---------------- 1. pack H -> bits, COALESCED: wave = half row ----------------
// blocks 0..15 also zero de_cnt (accumulated by k_mm1 atomics, later dispatch).
__global__ __launch_bounds__(256) void k_pack(const int* __restrict__ H,
                                              unsigned* __restrict__ packed,
                                              float* __restrict__ dv,
                                              int* __restrict__ de_cnt) {
    __shared__ int cl[4];
    int t = threadIdx.x, wave = t >> 6, lane = t & 63;
    if (blockIdx.x < 16) de_cnt[blockIdx.x * 256 + t] = 0;
    int row = blockIdx.x * 2 + (wave >> 1);
    int half = wave & 1;
    const uint4* base = reinterpret_cast<const uint4*>(H) + (size_t)row * 1024 + half * 512 + lane * 8;
    unsigned m = 0;
#pragma unroll
    for (int i = 0; i < 8; ++i) {
        uint4 v = base[i];
        m |= (v.x ? 1u : 0u) << (i * 4 + 0);
        m |= (v.y ? 1u : 0u) << (i * 4 + 1);
        m |= (v.z ? 1u : 0u) << (i * 4 + 2);
        m |= (v.w ? 1u : 0u) << (i * 4 + 3);
    }
    packed[(size_t)row * NW_E + half * 64 + lane] = m;
    int c = __popc(m);
    for (int o = 32; o > 0; o >>= 1) c += __shfl_down(c, o, 64);
    if (lane == 0) cl[wave] = c;
    __syncthreads();
    if (t < 2) {
        int d = cl[t * 2] + cl[t * 2 + 1];
        dv[blockIdx.x * 2 + t] = d > 0 ? 1.0f / sqrtf((float)d) : 1.0f;
    }
}

// ---------------- 2. At[kc2][f][c-swz] = bf16(dv*X), PRE-SWIZZLED for cp16 ----------------
// n >= 20000 zero-filled: zero A-column guarantees pad-n contributions vanish in mm1.
__global__ __launch_bounds__(256) void k_mid(const float* __restrict__ X,
                                             const float* __restrict__ dv,
                                             unsigned short* __restrict__ At) {
    int t = threadIdx.x;
    int f = t & 127;
    int item = blockIdx.x * 2 + (t >> 7);     // 0..2511, 8 n each (2512*8 = 20096)
    int nbase = item * 8;
    unsigned short h[8];
#pragma unroll
    for (int i = 0; i < 8; ++i) {
        int n = nbase + i;
        float v = (n < NV) ? X[(size_t)n * FT + f] * dv[n] : 0.0f;
        h[i] = f2bf(v);
    }
    uint4 u;
    u.x = (unsigned)h[0] | ((unsigned)h[1] << 16);
    u.y = (unsigned)h[2] | ((unsigned)h[3] << 16);
    u.z = (unsigned)h[4] | ((unsigned)h[5] << 16);
    u.w = (unsigned)h[6] | ((unsigned)h[7] << 16);
    int kc2 = nbase >> 7;
    int c = (nbase >> 3) & 15;
    *reinterpret_cast<uint4*>(At + (size_t)kc2 * 16384 + f * 128 + ((c ^ (f & 15)) << 3)) = u;
}

// ---------------- 3. mm1: P[kp][e][f] = sum_n At[f][n] * H[n][e], split-K ----------------
// B bits come straight from `packed`, transposed IN-REGISTER via shfl_xor butterfly
// during staging; VALU-expanded to bf16 (no LUT). Edge degrees accumulate in regs.
__global__ __launch_bounds__(256, 2) void k_mm1(const unsigned short* __restrict__ At,
                                                const unsigned* __restrict__ packed,
                                                float* __restrict__ P,
                                                int* __restrict__ de_cnt, int chunkK) {
    __shared__ __align__(16) unsigned char sA[32768];   // 128 f x 128 n bf16 (swz)
    __shared__ __align__(16) unsigned char sB[32768];   // 128 e x 128 n bf16 (swz)
    int t = threadIdx.x;

    int et = blockIdx.x & 31, kp = blockIdx.x >> 5;
    int e0 = et * 128;
    int kbeg = kp * chunkK;
    int kend = kbeg + chunkK; if (kend > K_TOT) kend = K_TOT;
    int iters = (kend - kbeg) >> 7; if (iters < 0) iters = 0;

    float4v acc[4][4];
#pragma unroll
    for (int i = 0; i < 4; ++i)
#pragma unroll
        for (int j = 0; j < 4; ++j)
#pragma unroll
            for (int r = 0; r < 4; ++r) acc[i][j][r] = 0.0f;

    int wave = t >> 6, lane = t & 63;
    int wm0 = (wave & 1) * 64, wc0 = (wave >> 1) * 64;
    int r0 = lane & 15, q = lane >> 4;

    // B-staging: 8 groups of 32 lanes. group g: n-subgroup ns=g&3 (32 n),
    // word pair wbase=(g>>2)*2 -> e-rows [wbase*32, wbase*32+64).
    int grp = t >> 5, l32 = t & 31;
    int ns = grp & 3;
    int wbase = (grp >> 2) * 2;
    int ecol = et * 4 + wbase;          // even -> uint2-aligned
    int de_c0 = 0, de_c1 = 0;

    auto ldB = [&](int it) {
        uint2 v; v.x = 0u; v.y = 0u;
        int n = kbeg + it * 128 + ns * 32 + l32;
        if (n < NV) v = *reinterpret_cast<const uint2*>(packed + (size_t)n * NW_E + ecol);
        return v;
    };
    uint2 bw; bw.x = 0u; bw.y = 0u;
    if (iters > 0) bw = ldB(0);

    const char* gA = reinterpret_cast<const char*>(At) + (size_t)(kbeg >> 7) * 32768 + wave * 8192 + lane * 16;
    char* lA = reinterpret_cast<char*>(sA) + wave * 8192;

    int rB0 = wbase * 32 + l32;         // e_local for word wbase
    int rB1 = rB0 + 32;                 // e_local for word wbase+1

    for (int it = 0; it < iters; ++it) {
        // A: 32KB async DMA (each wave 8x1KB, linear dest = pre-swizzled layout)
        const char* g = gA + (size_t)it * 32768;
#pragma unroll
        for (int j = 0; j < 8; ++j) cp16(lA + j * 1024, g + j * 1024);
        // B: prefetch next words, transpose current in-register, VALU-expand to sB
        uint2 nxt; nxt.x = 0u; nxt.y = 0u;
        if (it + 1 < iters) nxt = ldB(it + 1);
        {
            unsigned x0 = bt32(bw.x, lane);
            unsigned x1 = bt32(bw.y, lane);
            de_c0 += __popc(x0);
            de_c1 += __popc(x1);
#pragma unroll
            for (int c = 0; c < 4; ++c)
                *reinterpret_cast<uint4*>(sB + lds_off(rB0, ns * 4 + c)) = expand8v(x0 >> (c * 8));
#pragma unroll
            for (int c = 0; c < 4; ++c)
                *reinterpret_cast<uint4*>(sB + lds_off(rB1, ns * 4 + c)) = expand8v(x1 >> (c * 8));
            bw = nxt;
        }
        __syncthreads();
#pragma unroll
        for (int ks = 0; ks < 4; ++ks) {
            short8v a[4], bb[4];
#pragma unroll
            for (int mi = 0; mi < 4; ++mi)
                a[mi] = *reinterpret_cast<const short8v*>(sA + lds_off(wm0 + mi * 16 + r0, ks * 4 + q));
#pragma unroll
            for (int ci = 0; ci < 4; ++ci)
                bb[ci] = *reinterpret_cast<const short8v*>(sB + lds_off(wc0 + ci * 16 + r0, ks * 4 + q));
#pragma unroll
            for (int mi = 0; mi < 4; ++mi)
#pragma unroll
                for (int ci = 0; ci < 4; ++ci)
                    acc[mi][ci] = __builtin_amdgcn_mfma_f32_16x16x32_bf16(a[mi], bb[ci], acc[mi][ci], 0, 0, 0);
        }
        __syncthreads();
    }
    // flush per-lane edge-degree partials (each lane owns 2 fixed e-rows)
    atomicAdd(de_cnt + e0 + rB0, de_c0);
    atomicAdd(de_cnt + e0 + rB1, de_c1);
    // e-major epilogue: one float4 store per fragment (f = r contiguous)
    float* Pp = P + (size_t)kp * (4096 * 128);
#pragma unroll
    for (int mi = 0; mi < 4; ++mi)
#pragma unroll
        for (int ci = 0; ci < 4; ++ci) {
            int f = wm0 + mi * 16 + q * 4;
            int e = e0 + wc0 + ci * 16 + r0;
            *reinterpret_cast<float4v*>(Pp + (size_t)e * 128 + f) = acc[mi][ci];
        }
}

// ---------------- 4. fused reduce + (T^T W)^T * de -> Ut slabs ----------------
// P is [kp][e][f] (e-major): reduce reads are 512B-contiguous rows.
__global__ __launch_bounds__(256) void k_redut(const float* __restrict__ P,
                                               const float* __restrict__ W,
                                               const int* __restrict__ de_cnt,
                                               unsigned short* __restrict__ Ut, int S) {
    __shared__ float sT[8][132];    // +4 pad: W-phase reads conflict-free
    int t = threadIdx.x;
    int e0 = blockIdx.x * 8;
    {
        int el = t >> 5, fq = (t & 31) * 4;
        const float* base = P + (size_t)(e0 + el) * 128 + fq;
        float4 s = {0.f, 0.f, 0.f, 0.f};
        for (int p = 0; p < S; ++p) {
            float4 v = *reinterpret_cast<const float4*>(base + (size_t)p * 524288);
            s.x += v.x; s.y += v.y; s.z += v.z; s.w += v.w;
        }
        *reinterpret_cast<float4*>(&sT[el][fq]) = s;
    }
    __syncthreads();
    int el = t & 7, gq = (t >> 3) * 4;
    int e = e0 + el;
    float a0 = 0, a1 = 0, a2 = 0, a3 = 0;
    for (int f = 0; f < 128; ++f) {
        float tv = sT[el][f];
        float4 wv = *reinterpret_cast<const float4*>(W + f * 128 + gq);
        a0 += tv * wv.x; a1 += tv * wv.y; a2 += tv * wv.z; a3 += tv * wv.w;
    }
    int cnt = de_cnt[e];
    float d = cnt > 0 ? 1.0f / (float)cnt : 1.0f;
    float av[4] = {a0, a1, a2, a3};
    int slabB = e >> 7, chi = (e >> 3) & 15, pos = e & 7;
#pragma unroll
    for (int k = 0; k < 4; ++k) {
        int g = gq + k, qg = g >> 5, gr = g & 31;
        Ut[(size_t)(qg * 32 + slabB) * 4096 + gr * 128 + ((chi ^ (gr & 15)) << 3) + pos] = f2bf(av[k] * d);
    }
}

// ---------------- 5. mm2: out[n][g] = dv[n]*sum_e H[n][e]*U[g][e] + bias[g] ----------------
// R3-proven structure; A bit-expansion via VALU (no LUT); B via cp16 on waves 0-1.
__global__ __launch_bounds__(256, 3) void k_mm2(const unsigned* __restrict__ packed,
                                                const unsigned short* __restrict__ Ut,
                                                const float* __restrict__ dv,
                                                const float* __restrict__ bias,
                                                float* __restrict__ out) {
    __shared__ __align__(16) unsigned char sA[32768];   // 128 n x 128 e bf16 (swz)
    __shared__ __align__(16) unsigned char sB[8192];    //  32 g x 128 e bf16 (swz)
    int t = threadIdx.x;

    int mt = blockIdx.x >> 2, qg = blockIdx.x & 3;
    int n0 = mt * 128, g0 = qg * 32;

    float4v acc[4];
#pragma unroll
    for (int i = 0; i < 4; ++i)
#pragma unroll
        for (int r = 0; r < 4; ++r) acc[i][r] = 0.0f;

    int wave = t >> 6, lane = t & 63;
    int wm0 = (wave & 1) * 64, wc0 = (wave >> 1) * 16;
    int r0 = lane & 15, q = lane >> 4;

    int rA = t & 127, half = t >> 7, cb = half << 3;
    const uint4* arow4 = reinterpret_cast<const uint4*>(packed + (size_t)(n0 + rA) * NW_E);
    uint4 aw = arow4[0];   // rows >= NV read in-ws garbage; outputs guarded

    const char* gB = reinterpret_cast<const char*>(Ut) + (size_t)(qg * 32) * 8192 + (wave & 1) * 4096 + lane * 16;
    char* lB = reinterpret_cast<char*>(sB) + (wave & 1) * 4096;

    for (int it = 0; it < 32; ++it) {
        uint4 nxt = arow4[it + 1];          // 16B over-read at it=31 stays in ws, never consumed
        if (wave < 2) {
            const char* g = gB + (size_t)it * 8192;
#pragma unroll
            for (int j = 0; j < 4; ++j) cp16(lB + j * 1024, g + j * 1024);
        }
        {
            unsigned wd0 = half ? aw.z : aw.x;
            unsigned wd1 = half ? aw.w : aw.y;
#pragma unroll
            for (int c = 0; c < 4; ++c)
                *reinterpret_cast<uint4*>(sA + lds_off(rA, cb + c)) = expand8v(wd0 >> (c * 8));
#pragma unroll
            for (int c = 0; c < 4; ++c)
                *reinterpret_cast<uint4*>(sA + lds_off(rA, cb + 4 + c)) = expand8v(wd1 >> (c * 8));
            aw = nxt;
        }
        __syncthreads();
#pragma unroll
        for (int ks = 0; ks < 4; ++ks) {
            short8v a[4], bb;
#pragma unroll
            for (int mi = 0; mi < 4; ++mi)
                a[mi] = *reinterpret_cast<const short8v*>(sA + lds_off(wm0 + mi * 16 + r0, ks * 4 + q));
            bb = *reinterpret_cast<const short8v*>(sB + lds_off(wc0 + r0, ks * 4 + q));
#pragma unroll
            for (int mi = 0; mi < 4; ++mi)
                acc[mi] = __builtin_amdgcn_mfma_f32_16x16x32_bf16(a[mi], bb, acc[mi], 0, 0, 0);
        }
        __syncthreads();
    }
    {
        int g = g0 + wc0 + r0;
        float bg = bias[g];
#pragma unroll
        for (int mi = 0; mi < 4; ++mi) {
#pragma unroll
            for (int r = 0; r < 4; ++r) {
                int n = n0 + wm0 + mi * 16 + q * 4 + r;
                if (n < NV) out[(size_t)n * 128 + g] = dv[n] * acc[mi][r] + bg;
            }
        }
    }
}

extern "C" void kernel_launch(void* const* d_in, const int* in_sizes, int n_in,
                              void* d_out, int out_size, void* d_ws, size_t ws_size,
                              hipStream_t stream) {
    const float* X    = (const float*)d_in[0];
    const int*   H    = (const int*)d_in[1];
    const float* W    = (const float*)d_in[2];
    const float* bias = (const float*)d_in[3];
    float* out = (float*)d_out;

    char* ws = (char*)d_ws;
    size_t off = 0;
    auto alloc = [&](size_t sz) { char* p = ws + off; off += (sz + 255) & ~(size_t)255; return p; };
    unsigned*       packed  = (unsigned*)alloc((size_t)NV * NW_E * 4);           // 10.24 MB
    unsigned short* At      = (unsigned short*)alloc((size_t)NKC2 * 16384 * 2);  //  5.14 MB
    unsigned short* Ut      = (unsigned short*)alloc((size_t)FT * NE * 2);       //  1.05 MB
    float*          dv      = (float*)alloc((size_t)NV * 4);
    int*            de_cnt  = (int*)alloc((size_t)NE * 4);
    size_t fixed = off;

    long long avail = (long long)ws_size - (long long)fixed;
    int S = (int)(avail / (128LL * 4096 * 4));
    if (S > 16) S = 16;
    if (S < 1) S = 1;
    float* P1 = (float*)(ws + fixed);
    int chunkK = ((NKC2 + S - 1) / S) * 128;

    k_pack  <<<NV / 2, 256, 0, stream>>>(H, packed, dv, de_cnt);
    k_mid   <<<1256, 256, 0, stream>>>(X, dv, At);
    k_mm1   <<<32 * S, 256, 0, stream>>>(At, packed, P1, de_cnt, chunkK);
    k_redut <<<512, 256, 0, stream>>>(P1, W, de_cnt, Ut, S);
    k_mm2   <<<628, 256, 0, stream>>>(packed, Ut, dv, bias, out);
}

// Round 6
// 546.514 us; speedup vs baseline: 1.0436x; 1.0235x over previous
//
#include <hip/hip_runtime.h>

#define NV 20000          // vertices
#define NE 4096           // hyperedges
#define FT 128            // features
#define NW_E 128          // u32 words per packed vertex row  (E/32)
#define NKC2 157          // 128-wide n-chunks (157*128 = 20096)
#define K_TOT 20096
#define NPAD 20096        // padded n extent for P2 rows

typedef __attribute__((ext_vector_type(8))) short short8v;   // 8 bf16 — MFMA A/B frag
typedef __attribute__((ext_vector_type(4))) float float4v;   // 4 fp32 — MFMA C/D frag

__device__ __forceinline__ unsigned short f2bf(float f) {    // fp32 -> bf16 RNE
    unsigned u = __float_as_uint(f);
    u += 0x7FFFu + ((u >> 16) & 1u);
    return (unsigned short)(u >> 16);
}
// LDS tile: rows of 128 bf16 (256B), 16B chunks XOR-swizzled by row (c ^ r&15).
__device__ __forceinline__ int lds_off(int r, int c) {
    return r * 256 + ((c ^ (r & 15)) << 4);
}
// VALU bit->bf16 expansion: 8 bits -> 8 bf16 in {0.0, 1.0} (16B).
__device__ __forceinline__ uint4 expand8v(unsigned b) {
    uint4 e;
    e.x = ((b & 1u)   ? 0x3F80u : 0u) | ((b & 2u)   ? 0x3F800000u : 0u);
    e.y = ((b & 4u)   ? 0x3F80u : 0u) | ((b & 8u)   ? 0x3F800000u : 0u);
    e.z = ((b & 16u)  ? 0x3F80u : 0u) | ((b & 32u)  ? 0x3F800000u : 0u);
    e.w = ((b & 64u)  ? 0x3F80u : 0u) | ((b & 128u) ? 0x3F800000u : 0u);
    return e;
}
// async 16B global->LDS. LDS dest = wave-uniform base + lane*16; producers
// pre-swizzle the GLOBAL layout so linear copy == swizzled LDS.
__device__ __forceinline__ void cp16(void* l, const void* g) {
    __builtin_amdgcn_global_load_lds((__attribute__((address_space(1))) void*)g,
                                     (__attribute__((address_space(3))) void*)l, 16, 0, 0);
}
// 32x32 bit transpose across each 32-lane half:
// input: lane i holds row i's 32 bits; output: lane j holds column j's 32 bits.
__device__ __forceinline__ unsigned bt32(unsigned x, int lane) {
    unsigned y;
    y = __shfl_xor(x, 16, 64);
    x = (lane & 16) ? ((x & 0xFFFF0000u) | ((y >> 16) & 0x0000FFFFu))
                    : ((x & 0x0000FFFFu) | ((y << 16) & 0xFFFF0000u));
    y = __shfl_xor(x, 8, 64);
    x = (lane & 8)  ? ((x & 0xFF00FF00u) | ((y >> 8) & 0x00FF00FFu))
                    : ((x & 0x00FF00FFu) | ((y << 8) & 0xFF00FF00u));
    y = __shfl_xor(x, 4, 64);
    x = (lane & 4)  ? ((x & 0xF0F0F0F0u) | ((y >> 4) & 0x0F0F0F0Fu))
                    : ((x & 0x0F0F0F0Fu) | ((y << 4) & 0xF0F0F0F0u));
    y = __shfl_xor(x, 2, 64);
    x = (lane & 2)  ? ((x & 0xCCCCCCCCu) | ((y >> 2) & 0x33333333u))
                    : ((x & 0x33333333u) | ((y << 2) & 0xCCCCCCCCu));
    y = __shfl_xor(x, 1, 64);
    x = (lane & 1)  ? ((x & 0xAAAAAAAAu) | ((y >> 1) & 0x55555555u))
                    : ((x & 0x55555555u) | ((y << 1) & 0xAAAAAAAAu));
    return x;
}

// ---------------- 1. pack H -> bits, COALESCED: wave = half row ----------------
// blocks 0..15 also zero de_cnt (accumulated by k_mm1 atomics, later dispatch).
__global__ __launch_bounds__(256) void k_pack(const int* __restrict__ H,
                                              unsigned* __restrict__ packed,
                                              float* __restrict__ dv,
                                              int* __restrict__ de_cnt) {
    __shared__ int cl[4];
    int t = threadIdx.x, wave = t >> 6, lane = t & 63;
    if (blockIdx.x < 16) de_cnt[blockIdx.x * 256 + t] = 0;
    int row = blockIdx.x * 2 + (wave >> 1);
    int half = wave & 1;
    const uint4* base = reinterpret_cast<const uint4*>(H) + (size_t)row * 1024 + half * 512 + lane * 8;
    unsigned m = 0;
#pragma unroll
    for (int i = 0; i < 8; ++i) {
        uint4 v = base[i];
        m |= (v.x ? 1u : 0u) << (i * 4 + 0);
        m |= (v.y ? 1u : 0u) << (i * 4 + 1);
        m |= (v.z ? 1u : 0u) << (i * 4 + 2);
        m |= (v.w ? 1u : 0u) << (i * 4 + 3);
    }
    packed[(size_t)row * NW_E + half * 64 + lane] = m;
    int c = __popc(m);
    for (int o = 32; o > 0; o >>= 1) c += __shfl_down(c, o, 64);
    if (lane == 0) cl[wave] = c;
    __syncthreads();
    if (t < 2) {
        int d = cl[t * 2] + cl[t * 2 + 1];
        dv[blockIdx.x * 2 + t] = d > 0 ? 1.0f / sqrtf((float)d) : 1.0f;
    }
}

// ---------------- 2. At[kc2][f][c-swz] = bf16(dv*X), PRE-SWIZZLED for cp16 ----------------
// n >= 20000 zero-filled: zero A-column guarantees pad-n contributions vanish in mm1.
__global__ __launch_bounds__(256) void k_mid(const float* __restrict__ X,
                                             const float* __restrict__ dv,
                                             unsigned short* __restrict__ At) {
    int t = threadIdx.x;
    int f = t & 127;
    int item = blockIdx.x * 2 + (t >> 7);     // 0..2511, 8 n each (2512*8 = 20096)
    int nbase = item * 8;
    unsigned short h[8];
#pragma unroll
    for (int i = 0; i < 8; ++i) {
        int n = nbase + i;
        float v = (n < NV) ? X[(size_t)n * FT + f] * dv[n] : 0.0f;
        h[i] = f2bf(v);
    }
    uint4 u;
    u.x = (unsigned)h[0] | ((unsigned)h[1] << 16);
    u.y = (unsigned)h[2] | ((unsigned)h[3] << 16);
    u.z = (unsigned)h[4] | ((unsigned)h[5] << 16);
    u.w = (unsigned)h[6] | ((unsigned)h[7] << 16);
    int kc2 = nbase >> 7;
    int c = (nbase >> 3) & 15;
    *reinterpret_cast<uint4*>(At + (size_t)kc2 * 16384 + f * 128 + ((c ^ (f & 15)) << 3)) = u;
}

// ---------------- 3. mm1: P[kp][e][f] = sum_n At[f][n] * H[n][e], split-K ----------------
// B bits come straight from `packed`, transposed IN-REGISTER via shfl_xor butterfly
// during staging; VALU-expanded to bf16. Edge degrees accumulate in regs.
__global__ __launch_bounds__(256, 2) void k_mm1(const unsigned short* __restrict__ At,
                                                const unsigned* __restrict__ packed,
                                                float* __restrict__ P,
                                                int* __restrict__ de_cnt, int chunkK) {
    __shared__ __align__(16) unsigned char sA[32768];   // 128 f x 128 n bf16 (swz)
    __shared__ __align__(16) unsigned char sB[32768];   // 128 e x 128 n bf16 (swz)
    int t = threadIdx.x;

    int et = blockIdx.x & 31, kp = blockIdx.x >> 5;
    int e0 = et * 128;
    int kbeg = kp * chunkK;
    int kend = kbeg + chunkK; if (kend > K_TOT) kend = K_TOT;
    int iters = (kend - kbeg) >> 7; if (iters < 0) iters = 0;

    float4v acc[4][4];
#pragma unroll
    for (int i = 0; i < 4; ++i)
#pragma unroll
        for (int j = 0; j < 4; ++j)
#pragma unroll
            for (int r = 0; r < 4; ++r) acc[i][j][r] = 0.0f;

    int wave = t >> 6, lane = t & 63;
    int wm0 = (wave & 1) * 64, wc0 = (wave >> 1) * 64;
    int r0 = lane & 15, q = lane >> 4;

    // B-staging: 8 groups of 32 lanes. group g: n-subgroup ns=g&3 (32 n),
    // word pair wbase=(g>>2)*2 -> e-rows [wbase*32, wbase*32+64).
    int grp = t >> 5, l32 = t & 31;
    int ns = grp & 3;
    int wbase = (grp >> 2) * 2;
    int ecol = et * 4 + wbase;          // even -> uint2-aligned
    int de_c0 = 0, de_c1 = 0;

    auto ldB = [&](int it) {
        uint2 v; v.x = 0u; v.y = 0u;
        int n = kbeg + it * 128 + ns * 32 + l32;
        if (n < NV) v = *reinterpret_cast<const uint2*>(packed + (size_t)n * NW_E + ecol);
        return v;
    };
    uint2 bw; bw.x = 0u; bw.y = 0u;
    if (iters > 0) bw = ldB(0);

    const char* gA = reinterpret_cast<const char*>(At) + (size_t)(kbeg >> 7) * 32768 + wave * 8192 + lane * 16;
    char* lA = reinterpret_cast<char*>(sA) + wave * 8192;

    int rB0 = wbase * 32 + l32;         // e_local for word wbase
    int rB1 = rB0 + 32;                 // e_local for word wbase+1

    for (int it = 0; it < iters; ++it) {
        // A: 32KB async DMA (each wave 8x1KB, linear dest = pre-swizzled layout)
        const char* g = gA + (size_t)it * 32768;
#pragma unroll
        for (int j = 0; j < 8; ++j) cp16(lA + j * 1024, g + j * 1024);
        // B: prefetch next words, transpose current in-register, VALU-expand to sB
        uint2 nxt; nxt.x = 0u; nxt.y = 0u;
        if (it + 1 < iters) nxt = ldB(it + 1);
        {
            unsigned x0 = bt32(bw.x, lane);
            unsigned x1 = bt32(bw.y, lane);
            de_c0 += __popc(x0);
            de_c1 += __popc(x1);
#pragma unroll
            for (int c = 0; c < 4; ++c)
                *reinterpret_cast<uint4*>(sB + lds_off(rB0, ns * 4 + c)) = expand8v(x0 >> (c * 8));
#pragma unroll
            for (int c = 0; c < 4; ++c)
                *reinterpret_cast<uint4*>(sB + lds_off(rB1, ns * 4 + c)) = expand8v(x1 >> (c * 8));
            bw = nxt;
        }
        __syncthreads();
#pragma unroll
        for (int ks = 0; ks < 4; ++ks) {
            short8v a[4], bb[4];
#pragma unroll
            for (int mi = 0; mi < 4; ++mi)
                a[mi] = *reinterpret_cast<const short8v*>(sA + lds_off(wm0 + mi * 16 + r0, ks * 4 + q));
#pragma unroll
            for (int ci = 0; ci < 4; ++ci)
                bb[ci] = *reinterpret_cast<const short8v*>(sB + lds_off(wc0 + ci * 16 + r0, ks * 4 + q));
#pragma unroll
            for (int mi = 0; mi < 4; ++mi)
#pragma unroll
                for (int ci = 0; ci < 4; ++ci)
                    acc[mi][ci] = __builtin_amdgcn_mfma_f32_16x16x32_bf16(a[mi], bb[ci], acc[mi][ci], 0, 0, 0);
        }
        __syncthreads();
    }
    // flush per-lane edge-degree partials (each lane owns 2 fixed e-rows)
    atomicAdd(de_cnt + e0 + rB0, de_c0);
    atomicAdd(de_cnt + e0 + rB1, de_c1);
    // e-major epilogue: one float4 store per fragment (f = r contiguous)
    float* Pp = P + (size_t)kp * (4096 * 128);
#pragma unroll
    for (int mi = 0; mi < 4; ++mi)
#pragma unroll
        for (int ci = 0; ci < 4; ++ci) {
            int f = wm0 + mi * 16 + q * 4;
            int e = e0 + wc0 + ci * 16 + r0;
            *reinterpret_cast<float4v*>(Pp + (size_t)e * 128 + f) = acc[mi][ci];
        }
}

// ---------------- 4. fused reduce + (T^T W)^T * de -> Ut slabs ----------------
// P is [kp][e][f] (e-major): reduce reads are 512B-contiguous rows.
__global__ __launch_bounds__(256) void k_redut(const float* __restrict__ P,
                                               const float* __restrict__ W,
                                               const int* __restrict__ de_cnt,
                                               unsigned short* __restrict__ Ut, int S) {
    __shared__ float sT[8][132];    // +4 pad: W-phase reads conflict-free
    int t = threadIdx.x;
    int e0 = blockIdx.x * 8;
    {
        int el = t >> 5, fq = (t & 31) * 4;
        const float* base = P + (size_t)(e0 + el) * 128 + fq;
        float4 s = {0.f, 0.f, 0.f, 0.f};
        for (int p = 0; p < S; ++p) {
            float4 v = *reinterpret_cast<const float4*>(base + (size_t)p * 524288);
            s.x += v.x; s.y += v.y; s.z += v.z; s.w += v.w;
        }
        *reinterpret_cast<float4*>(&sT[el][fq]) = s;
    }
    __syncthreads();
    int el = t & 7, gq = (t >> 3) * 4;
    int e = e0 + el;
    float a0 = 0, a1 = 0, a2 = 0, a3 = 0;
    for (int f = 0; f < 128; ++f) {
        float tv = sT[el][f];
        float4 wv = *reinterpret_cast<const float4*>(W + f * 128 + gq);
        a0 += tv * wv.x; a1 += tv * wv.y; a2 += tv * wv.z; a3 += tv * wv.w;
    }
    int cnt = de_cnt[e];
    float d = cnt > 0 ? 1.0f / (float)cnt : 1.0f;
    float av[4] = {a0, a1, a2, a3};
    int slabB = e >> 7, chi = (e >> 3) & 15, pos = e & 7;
#pragma unroll
    for (int k = 0; k < 4; ++k) {
        int g = gq + k, qg = g >> 5, gr = g & 31;
        Ut[(size_t)(qg * 32 + slabB) * 4096 + gr * 128 + ((chi ^ (gr & 15)) << 3) + pos] = f2bf(av[k] * d);
    }
}

// ---------------- 5. mm2: P2[es][n][g] = sum_{e in chunk} H[n][e]*U[g][e] ----------------
// 128n x 128g block, e-split 4 (R4 structure: 2.3x lower LDS/MFMA, 4x lower A-gather
// than the 128x32 shape) with PLAIN partial stores — no atomics (R4's regression source).
__global__ __launch_bounds__(256, 2) void k_mm2(const unsigned* __restrict__ packed,
                                                const unsigned short* __restrict__ Ut,
                                                float* __restrict__ P2) {
    __shared__ __align__(16) unsigned char sA[32768];   // 128 n x 128 e bf16 (swz)
    __shared__ __align__(16) unsigned char sB[32768];   // 128 g x 128 e bf16 (swz)
    int t = threadIdx.x;

    int mt = blockIdx.x >> 2, es = blockIdx.x & 3;   // n-stripe, e-chunk (1024 e)
    int n0 = mt * 128;

    float4v acc[4][4];
#pragma unroll
    for (int i = 0; i < 4; ++i)
#pragma unroll
        for (int j = 0; j < 4; ++j)
#pragma unroll
            for (int r = 0; r < 4; ++r) acc[i][j][r] = 0.0f;

    int wave = t >> 6, lane = t & 63;
    int wm0 = (wave & 1) * 64, wg0 = (wave >> 1) * 64;
    int r0 = lane & 15, q = lane >> 4;

    int rA = t & 127, half = t >> 7, cb = half << 3;
    const uint4* arow4 = reinterpret_cast<const uint4*>(packed + (size_t)(n0 + rA) * NW_E) + es * 8;
    uint4 aw = arow4[0];   // rows >= NV read in-ws garbage; partial rows n>=NV never read back

    // B: wave w stages the 32-g slab qg=w of e-block (es*8+it): 8KB via 8 cp16/lane
    const char* gB = reinterpret_cast<const char*>(Ut) + ((size_t)wave * 32 + es * 8) * 8192 + lane * 16;
    char* lB = reinterpret_cast<char*>(sB) + wave * 8192;

    for (int it = 0; it < 8; ++it) {
        uint4 nxt = arow4[it + 1];      // 16B over-read at last iter stays in ws, never consumed
        {
            const char* g = gB + (size_t)it * 8192;
#pragma unroll
            for (int j = 0; j < 8; ++j) cp16(lB + j * 1024, g + j * 1024);
        }
        {
            unsigned wd0 = half ? aw.z : aw.x;
            unsigned wd1 = half ? aw.w : aw.y;
#pragma unroll
            for (int c = 0; c < 4; ++c)
                *reinterpret_cast<uint4*>(sA + lds_off(rA, cb + c)) = expand8v(wd0 >> (c * 8));
#pragma unroll
            for (int c = 0; c < 4; ++c)
                *reinterpret_cast<uint4*>(sA + lds_off(rA, cb + 4 + c)) = expand8v(wd1 >> (c * 8));
            aw = nxt;
        }
        __syncthreads();
#pragma unroll
        for (int ks = 0; ks < 4; ++ks) {
            short8v a[4], bb[4];
#pragma unroll
            for (int mi = 0; mi < 4; ++mi)
                a[mi] = *reinterpret_cast<const short8v*>(sA + lds_off(wm0 + mi * 16 + r0, ks * 4 + q));
#pragma unroll
            for (int ci = 0; ci < 4; ++ci)
                bb[ci] = *reinterpret_cast<const short8v*>(sB + lds_off(wg0 + ci * 16 + r0, ks * 4 + q));
#pragma unroll
            for (int mi = 0; mi < 4; ++mi)
#pragma unroll
                for (int ci = 0; ci < 4; ++ci)
                    acc[mi][ci] = __builtin_amdgcn_mfma_f32_16x16x32_bf16(a[mi], bb[ci], acc[mi][ci], 0, 0, 0);
        }
        __syncthreads();
    }
    // plain partial store: P2[es][n][g] (n rows >= NV land in pad, never read)
    float* p = P2 + (size_t)es * NPAD * 128;
#pragma unroll
    for (int mi = 0; mi < 4; ++mi)
#pragma unroll
        for (int ci = 0; ci < 4; ++ci) {
            int g = wg0 + ci * 16 + r0;
#pragma unroll
            for (int r = 0; r < 4; ++r) {
                int n = n0 + wm0 + mi * 16 + q * 4 + r;
                p[(size_t)n * 128 + g] = acc[mi][ci][r];
            }
        }
}

// ---------------- 6. final: out[n][g] = dv[n]*sum_es P2[es][n][g] + bias[g] ----------------
__global__ __launch_bounds__(256) void k_final(const float* __restrict__ P2,
                                               const float* __restrict__ dv,
                                               const float* __restrict__ bias,
                                               float* __restrict__ out) {
    int i = blockIdx.x * 256 + threadIdx.x;   // NV*32 = 640000 float4s
    if (i >= NV * 32) return;
    int n = i >> 5, g4 = i & 31;
    const float4v* p = reinterpret_cast<const float4v*>(P2) + (size_t)n * 32 + g4;
    const size_t esS = (size_t)NPAD * 32;     // es stride in float4v units
    float4v s = p[0] + p[esS] + p[2 * esS] + p[3 * esS];
    float d = dv[n];
    float4v b = reinterpret_cast<const float4v*>(bias)[g4];
    reinterpret_cast<float4v*>(out)[(size_t)n * 32 + g4] = s * d + b;
}

extern "C" void kernel_launch(void* const* d_in, const int* in_sizes, int n_in,
                              void* d_out, int out_size, void* d_ws, size_t ws_size,
                              hipStream_t stream) {
    const float* X    = (const float*)d_in[0];
    const int*   H    = (const int*)d_in[1];
    const float* W    = (const float*)d_in[2];
    const float* bias = (const float*)d_in[3];
    float* out = (float*)d_out;

    char* ws = (char*)d_ws;
    size_t off = 0;
    auto alloc = [&](size_t sz) { char* p = ws + off; off += (sz + 255) & ~(size_t)255; return p; };
    unsigned*       packed  = (unsigned*)alloc((size_t)NV * NW_E * 4);           // 10.24 MB
    unsigned short* At      = (unsigned short*)alloc((size_t)NKC2 * 16384 * 2);  //  5.14 MB
    unsigned short* Ut      = (unsigned short*)alloc((size_t)FT * NE * 2);       //  1.05 MB
    float*          dv      = (float*)alloc((size_t)NV * 4);
    int*            de_cnt  = (int*)alloc((size_t)NE * 4);
    float*          P2      = (float*)alloc((size_t)4 * NPAD * 128 * 4);         // 41.2 MB
    size_t fixed = off;

    long long avail = (long long)ws_size - (long long)fixed;
    int S = (int)(avail / (128LL * 4096 * 4));
    if (S > 16) S = 16;
    if (S < 1) S = 1;
    float* P1 = (float*)(ws + fixed);
    int chunkK = ((NKC2 + S - 1) / S) * 128;

    k_pack  <<<NV / 2, 256, 0, stream>>>(H, packed, dv, de_cnt);
    k_mid   <<<1256, 256, 0, stream>>>(X, dv, At);
    k_mm1   <<<32 * S, 256, 0, stream>>>(At, packed, P1, de_cnt, chunkK);
    k_redut <<<512, 256, 0, stream>>>(P1, W, de_cnt, Ut, S);
    k_mm2   <<<628, 256, 0, stream>>>(packed, Ut, P2);
    k_final <<<2500, 256, 0, stream>>>(P2, dv, bias, out);
}